// Round 1
// baseline (959.434 us; speedup 1.0000x reference)
//
#include <hip/hip_runtime.h>
#include <cstdint>

using bf16x8 = __attribute__((ext_vector_type(8))) short;
using f32x4  = __attribute__((ext_vector_type(4))) float;

__device__ __forceinline__ unsigned short f2bf(float f) {
  union { float f; unsigned u; } v; v.f = f;
  unsigned u = v.u;
  u += 0x7fffu + ((u >> 16) & 1u);
  return (unsigned short)(u >> 16);
}

// ---------------- LayerNorm (row of 2048 f32) -> bf16 ----------------
__global__ __launch_bounds__(256) void ln_kernel(
    const float* __restrict__ x, const float* __restrict__ g,
    const float* __restrict__ bb, unsigned short* __restrict__ h)
{
  const int D = 2048;
  const int row = blockIdx.x;
  const float* xr = x + (size_t)row * D;
  const int t = threadIdx.x;
  float4 v0 = ((const float4*)xr)[t];
  float4 v1 = ((const float4*)xr)[t + 256];
  float s  = v0.x+v0.y+v0.z+v0.w + v1.x+v1.y+v1.z+v1.w;
  float ss = v0.x*v0.x+v0.y*v0.y+v0.z*v0.z+v0.w*v0.w
           + v1.x*v1.x+v1.y*v1.y+v1.z*v1.z+v1.w*v1.w;
  #pragma unroll
  for (int off = 1; off < 64; off <<= 1) {
    s  += __shfl_xor(s, off);
    ss += __shfl_xor(ss, off);
  }
  __shared__ float red[8];
  const int wave = t >> 6, lane = t & 63;
  if (lane == 0) { red[wave] = s; red[4+wave] = ss; }
  __syncthreads();
  s  = red[0]+red[1]+red[2]+red[3];
  ss = red[4]+red[5]+red[6]+red[7];
  const float mu   = s * (1.f/2048.f);
  const float var  = ss * (1.f/2048.f) - mu*mu;
  const float rstd = rsqrtf(var + 1e-5f);
  unsigned short* hr = h + (size_t)row * D;
  #pragma unroll
  for (int q = 0; q < 2; ++q) {
    float4 v = q ? v1 : v0;
    int vecidx = t + q*256;
    float4 gg  = ((const float4*)g)[vecidx];
    float4 bv  = ((const float4*)bb)[vecidx];
    ushort4 o;
    o.x = f2bf((v.x-mu)*rstd*gg.x + bv.x);
    o.y = f2bf((v.y-mu)*rstd*gg.y + bv.y);
    o.z = f2bf((v.z-mu)*rstd*gg.z + bv.z);
    o.w = f2bf((v.w-mu)*rstd*gg.w + bv.w);
    *(ushort4*)(hr + vecidx*4) = o;
  }
}

// ---------------- fp32 [K][N] -> bf16 [N][K] transpose+cast ----------------
__global__ __launch_bounds__(256) void transpose_cast(
    const float* __restrict__ W, unsigned short* __restrict__ WT,
    int K, int N)
{
  __shared__ float tile[32][33];
  const int tx = threadIdx.x, ty = threadIdx.y;
  const int n0 = blockIdx.x * 32, k0 = blockIdx.y * 32;
  #pragma unroll
  for (int r = 0; r < 4; ++r)
    tile[ty + r*8][tx] = W[(size_t)(k0 + ty + r*8) * N + n0 + tx];
  __syncthreads();
  #pragma unroll
  for (int r = 0; r < 4; ++r)
    WT[(size_t)(n0 + ty + r*8) * K + k0 + tx] = f2bf(tile[tx][ty + r*8]);
}

// ---------------- bf16 GEMM: C[M][N] = A[M][K] @ BT[N][K]^T (+epilogue) ----------------
template<bool BIAS, bool RELU, bool RESID, bool OUTBF16>
__global__ __launch_bounds__(256, 2) void gemm_bt(
    const unsigned short* __restrict__ A, const unsigned short* __restrict__ BT,
    const float* __restrict__ bias, const float* __restrict__ resid,
    void* __restrict__ Cp, int M, int N, int K)
{
  constexpr int BM = 128, BN = 128, BK = 64, PK = 72;  // +8 bf16 pad: 2-way bank conflicts (free)
  __shared__ __align__(16) unsigned short As[BM*PK];
  __shared__ __align__(16) unsigned short Bs[BN*PK];
  const int tid  = threadIdx.x;
  const int lane = tid & 63;
  const int wave = tid >> 6;
  const int l15 = lane & 15, lh = lane >> 4;
  const size_t bm = (size_t)blockIdx.y * BM, bn = (size_t)blockIdx.x * BN;
  const int wm = (wave >> 1) * 64, wn = (wave & 1) * 64;
  f32x4 acc[4][4] = {};
  bf16x8 ar[4], br[4];
  const int nk = K / BK;

  auto loadG = [&](int kt) {
    #pragma unroll
    for (int q = 0; q < 4; ++q) {
      int c = tid + q*256;
      int row = c >> 3, k0 = (c & 7) * 8;
      ar[q] = *(const bf16x8*)(A  + (bm + row)*(size_t)K + (size_t)kt*BK + k0);
      br[q] = *(const bf16x8*)(BT + (bn + row)*(size_t)K + (size_t)kt*BK + k0);
    }
  };
  loadG(0);
  for (int kt = 0; kt < nk; ++kt) {
    __syncthreads();
    #pragma unroll
    for (int q = 0; q < 4; ++q) {
      int c = tid + q*256;
      int row = c >> 3, k0 = (c & 7) * 8;
      *(bf16x8*)(&As[row*PK + k0]) = ar[q];
      *(bf16x8*)(&Bs[row*PK + k0]) = br[q];
    }
    __syncthreads();
    if (kt + 1 < nk) loadG(kt + 1);   // in flight during MFMAs
    #pragma unroll
    for (int kk = 0; kk < 2; ++kk) {
      bf16x8 af[4], bfr[4];
      #pragma unroll
      for (int i = 0; i < 4; ++i) {
        af[i]  = *(const bf16x8*)(&As[(wm + i*16 + l15)*PK + kk*32 + lh*8]);
        bfr[i] = *(const bf16x8*)(&Bs[(wn + i*16 + l15)*PK + kk*32 + lh*8]);
      }
      #pragma unroll
      for (int i = 0; i < 4; ++i)
        #pragma unroll
        for (int j = 0; j < 4; ++j)
          acc[i][j] = __builtin_amdgcn_mfma_f32_16x16x32_bf16(af[i], bfr[j], acc[i][j], 0, 0, 0);
    }
  }
  // epilogue
  float bv[4];
  if (BIAS) {
    #pragma unroll
    for (int j = 0; j < 4; ++j) bv[j] = bias[bn + wn + j*16 + l15];
  }
  #pragma unroll
  for (int i = 0; i < 4; ++i) {
    #pragma unroll
    for (int r = 0; r < 4; ++r) {
      size_t rrow = bm + wm + i*16 + lh*4 + r;
      #pragma unroll
      for (int j = 0; j < 4; ++j) {
        size_t ccol = bn + wn + j*16 + l15;
        float v = acc[i][j][r];
        if (BIAS)  v += bv[j];
        if (RELU)  v = fmaxf(v, 0.f);
        if (RESID) v += resid[rrow*(size_t)N + ccol];
        if (OUTBF16) ((unsigned short*)Cp)[rrow*(size_t)N + ccol] = f2bf(v);
        else         ((float*)Cp)[rrow*(size_t)N + ccol] = v;
      }
    }
  }
}

// ---------------- fused causal attention (scrambled head mapping) ----------------
// QKV: [4096][6144] bf16 (Q cols 0..2047, K 2048..4095, V 4096..6143)
// head nh, token i -> QKV row b*2048 + nh*128 + (i>>4), col chunk (i&15)*128
// O: [4096][2048] bf16, standard layout out[b][i][nh*128+dd]
__global__ __launch_bounds__(256) void attn_kernel(
    const unsigned short* __restrict__ QKV, unsigned short* __restrict__ O)
{
  constexpr float SCALE = 0.08838834764831845f;  // 1/sqrt(128)
  __shared__ __align__(16) unsigned short Vl[32*128];
  __shared__ __align__(16) unsigned short Pl[4*512];
  const int qt = blockIdx.x & 31;
  const int nh = (blockIdx.x >> 5) & 15;
  const int b  = blockIdx.x >> 9;
  const int t = threadIdx.x;
  const int lane = t & 63, wave = t >> 6;
  const int l15 = lane & 15, lh = lane >> 4;
  const int i0 = qt*64 + wave*16;
  const size_t RS = 6144;
  const size_t base = (size_t)b * 2048 * RS;

  const unsigned short* qrow = QKV + base + (size_t)(nh*128 + (i0 >> 4)) * RS;
  bf16x8 qf[4];
  #pragma unroll
  for (int c = 0; c < 4; ++c)
    qf[c] = *(const bf16x8*)(qrow + l15*128 + c*32 + lh*8);

  f32x4 of[8] = {};
  float mrun[4], lrun[4];
  #pragma unroll
  for (int r = 0; r < 4; ++r) { mrun[r] = -INFINITY; lrun[r] = 0.f; }

  const int nkt = qt*2 + 2;
  for (int kt = 0; kt < nkt; ++kt) {
    __syncthreads();
    // stage V tile [32 j][128 dd]
    #pragma unroll
    for (int q = 0; q < 2; ++q) {
      int c = t + q*256;
      int j = c >> 4, dd0 = (c & 15) * 8;
      const unsigned short* src = QKV + base
          + (size_t)(nh*128 + kt*2 + (j >> 4)) * RS + 4096 + (j & 15)*128 + dd0;
      *(bf16x8*)(&Vl[j*128 + dd0]) = *(const bf16x8*)src;
    }
    __syncthreads();
    if (kt*32 > i0 + 15) continue;   // tile fully masked for this wave

    // QK^T: 2 j-subtiles x 4 dd-chunks
    f32x4 sc[2] = {};
    #pragma unroll
    for (int jt = 0; jt < 2; ++jt) {
      const unsigned short* krow = QKV + base
          + (size_t)(nh*128 + kt*2 + jt) * RS + 2048;
      #pragma unroll
      for (int c = 0; c < 4; ++c) {
        bf16x8 kf = *(const bf16x8*)(krow + l15*128 + c*32 + lh*8);
        sc[jt] = __builtin_amdgcn_mfma_f32_16x16x32_bf16(qf[c], kf, sc[jt], 0, 0, 0);
      }
    }
    // online softmax (rows = lh*4+r, cols across lanes 0..15)
    const int j0 = kt*32 + l15, j1 = j0 + 16;
    float p0[4], p1[4], fac[4];
    #pragma unroll
    for (int r = 0; r < 4; ++r) {
      const int i = i0 + lh*4 + r;
      float s0 = (j0 > i) ? -INFINITY : sc[0][r]*SCALE;
      float s1 = (j1 > i) ? -INFINITY : sc[1][r]*SCALE;
      float mx = fmaxf(s0, s1);
      #pragma unroll
      for (int mk = 1; mk < 16; mk <<= 1) mx = fmaxf(mx, __shfl_xor(mx, mk));
      const float mnew = fmaxf(mrun[r], mx);
      p0[r] = __expf(s0 - mnew);
      p1[r] = __expf(s1 - mnew);
      float psum = p0[r] + p1[r];
      #pragma unroll
      for (int mk = 1; mk < 16; mk <<= 1) psum += __shfl_xor(psum, mk);
      fac[r]  = __expf(mrun[r] - mnew);
      lrun[r] = lrun[r]*fac[r] + psum;
      mrun[r] = mnew;
    }
    #pragma unroll
    for (int c = 0; c < 8; ++c)
      #pragma unroll
      for (int r = 0; r < 4; ++r)
        of[c][r] *= fac[r];
    // P (C-layout) -> LDS bf16 -> A-fragment
    unsigned short* pl = &Pl[wave*512];
    #pragma unroll
    for (int r = 0; r < 4; ++r) {
      pl[(lh*4 + r)*32 + l15]      = f2bf(p0[r]);
      pl[(lh*4 + r)*32 + 16 + l15] = f2bf(p1[r]);
    }
    bf16x8 pa = *(const bf16x8*)(pl + l15*32 + lh*8);
    // PV: o[16][128] += P[16][32] @ V[32][128]
    #pragma unroll
    for (int c = 0; c < 8; ++c) {
      bf16x8 vb;
      #pragma unroll
      for (int jj = 0; jj < 8; ++jj)
        vb[jj] = (short)Vl[(lh*8 + jj)*128 + c*16 + l15];
      of[c] = __builtin_amdgcn_mfma_f32_16x16x32_bf16(pa, vb, of[c], 0, 0, 0);
    }
  }
  // normalize + store
  unsigned short* orow = O + ((size_t)(b*2048 + i0))*2048 + nh*128;
  #pragma unroll
  for (int r = 0; r < 4; ++r) {
    const float inv = 1.f / lrun[r];
    #pragma unroll
    for (int c = 0; c < 8; ++c)
      orow[(size_t)(lh*4 + r)*2048 + c*16 + l15] = f2bf(of[c][r]*inv);
  }
}

// ---------------- launcher ----------------
extern "C" void kernel_launch(void* const* d_in, const int* in_sizes, int n_in,
                              void* d_out, int out_size, void* d_ws, size_t ws_size,
                              hipStream_t stream)
{
  const float* x    = (const float*)d_in[0];
  // d_in[1] = causal mask (implemented analytically)
  const float* Wq   = (const float*)d_in[2];
  const float* Wk   = (const float*)d_in[3];
  const float* Wv   = (const float*)d_in[4];
  const float* Wo   = (const float*)d_in[5];
  const float* ln1g = (const float*)d_in[6];
  const float* ln1b = (const float*)d_in[7];
  const float* W1   = (const float*)d_in[8];
  const float* b1   = (const float*)d_in[9];
  const float* W2   = (const float*)d_in[10];
  const float* b2   = (const float*)d_in[11];
  const float* ln2g = (const float*)d_in[12];
  const float* ln2b = (const float*)d_in[13];
  float* out = (float*)d_out;

  char* ws = (char*)d_ws;
  unsigned short* WqkvT  = (unsigned short*)(ws);                  // [6144][2048] bf16
  unsigned short* WoT    = (unsigned short*)(ws + 25165824);       // [2048][2048]
  unsigned short* W1T    = (unsigned short*)(ws + 33554432);       // [8192][2048]
  unsigned short* W2T    = (unsigned short*)(ws + 67108864);       // [2048][8192]
  unsigned short* h      = (unsigned short*)(ws + 100663296);      // [4096][2048] (h, then h2)
  float*          x2     = (float*)(ws + 117440512);               // [4096][2048] f32
  unsigned short* QKV    = (unsigned short*)(ws + 150994944);      // [4096][6144]
  unsigned short* attn_o = (unsigned short*)(ws + 201326592);      // [4096][2048]
  unsigned short* ff1    = (unsigned short*)(ws + 150994944);      // [4096][8192] aliases QKV+attn_o

  dim3 tb(32, 8);
  // weight transpose+cast (B^T bf16 layout)
  transpose_cast<<<dim3(64, 64),  tb, 0, stream>>>(Wq, WqkvT,                2048, 2048);
  transpose_cast<<<dim3(64, 64),  tb, 0, stream>>>(Wk, WqkvT + 2048*2048,    2048, 2048);
  transpose_cast<<<dim3(64, 64),  tb, 0, stream>>>(Wv, WqkvT + 2*2048*2048,  2048, 2048);
  transpose_cast<<<dim3(64, 64),  tb, 0, stream>>>(Wo, WoT,                  2048, 2048);
  transpose_cast<<<dim3(256, 64), tb, 0, stream>>>(W1, W1T,                  2048, 8192);
  transpose_cast<<<dim3(64, 256), tb, 0, stream>>>(W2, W2T,                  8192, 2048);

  // h = LN1(x)
  ln_kernel<<<4096, 256, 0, stream>>>(x, ln1g, ln1b, h);
  // QKV = h @ [Wq|Wk|Wv]
  gemm_bt<false,false,false,true><<<dim3(48, 32), 256, 0, stream>>>(
      h, WqkvT, nullptr, nullptr, QKV, 4096, 6144, 2048);
  // attention
  attn_kernel<<<1024, 256, 0, stream>>>(QKV, attn_o);
  // x2 = x + attn_o @ Wo
  gemm_bt<false,false,true,false><<<dim3(16, 32), 256, 0, stream>>>(
      attn_o, WoT, nullptr, x, x2, 4096, 2048, 2048);
  // h2 = LN2(x2)
  ln_kernel<<<4096, 256, 0, stream>>>(x2, ln2g, ln2b, h);
  // ff1 = relu(h2 @ W1 + b1)
  gemm_bt<true,true,false,true><<<dim3(64, 32), 256, 0, stream>>>(
      h, W1T, b1, nullptr, ff1, 4096, 8192, 2048);
  // out = x2 + ff1 @ W2 + b2
  gemm_bt<true,false,true,false><<<dim3(16, 32), 256, 0, stream>>>(
      ff1, W2T, b2, x2, out, 4096, 2048, 8192);
}

// Round 2
// 674.623 us; speedup vs baseline: 1.4222x; 1.4222x over previous
//
#include <hip/hip_runtime.h>
#include <cstdint>

using bf16x8 = __attribute__((ext_vector_type(8))) short;
using f32x4  = __attribute__((ext_vector_type(4))) float;

__device__ __forceinline__ unsigned short f2bf(float f) {
  union { float f; unsigned u; } v; v.f = f;
  unsigned u = v.u;
  u += 0x7fffu + ((u >> 16) & 1u);
  return (unsigned short)(u >> 16);
}

// ---------------- LayerNorm (row of 2048 f32) -> bf16 ----------------
__global__ __launch_bounds__(256) void ln_kernel(
    const float* __restrict__ x, const float* __restrict__ g,
    const float* __restrict__ bb, unsigned short* __restrict__ h)
{
  const int D = 2048;
  const int row = blockIdx.x;
  const float* xr = x + (size_t)row * D;
  const int t = threadIdx.x;
  float4 v0 = ((const float4*)xr)[t];
  float4 v1 = ((const float4*)xr)[t + 256];
  float s  = v0.x+v0.y+v0.z+v0.w + v1.x+v1.y+v1.z+v1.w;
  float ss = v0.x*v0.x+v0.y*v0.y+v0.z*v0.z+v0.w*v0.w
           + v1.x*v1.x+v1.y*v1.y+v1.z*v1.z+v1.w*v1.w;
  #pragma unroll
  for (int off = 1; off < 64; off <<= 1) {
    s  += __shfl_xor(s, off);
    ss += __shfl_xor(ss, off);
  }
  __shared__ float red[8];
  const int wave = t >> 6, lane = t & 63;
  if (lane == 0) { red[wave] = s; red[4+wave] = ss; }
  __syncthreads();
  s  = red[0]+red[1]+red[2]+red[3];
  ss = red[4]+red[5]+red[6]+red[7];
  const float mu   = s * (1.f/2048.f);
  const float var  = ss * (1.f/2048.f) - mu*mu;
  const float rstd = rsqrtf(var + 1e-5f);
  unsigned short* hr = h + (size_t)row * D;
  #pragma unroll
  for (int q = 0; q < 2; ++q) {
    float4 v = q ? v1 : v0;
    int vecidx = t + q*256;
    float4 gg  = ((const float4*)g)[vecidx];
    float4 bv  = ((const float4*)bb)[vecidx];
    ushort4 o;
    o.x = f2bf((v.x-mu)*rstd*gg.x + bv.x);
    o.y = f2bf((v.y-mu)*rstd*gg.y + bv.y);
    o.z = f2bf((v.z-mu)*rstd*gg.z + bv.z);
    o.w = f2bf((v.w-mu)*rstd*gg.w + bv.w);
    *(ushort4*)(hr + vecidx*4) = o;
  }
}

// ---------------- fp32 [K][N] -> bf16 [N][K] transpose+cast ----------------
__global__ __launch_bounds__(256) void transpose_cast(
    const float* __restrict__ W, unsigned short* __restrict__ WT,
    int K, int N)
{
  __shared__ float tile[32][33];
  const int tx = threadIdx.x, ty = threadIdx.y;
  const int n0 = blockIdx.x * 32, k0 = blockIdx.y * 32;
  #pragma unroll
  for (int r = 0; r < 4; ++r)
    tile[ty + r*8][tx] = W[(size_t)(k0 + ty + r*8) * N + n0 + tx];
  __syncthreads();
  #pragma unroll
  for (int r = 0; r < 4; ++r)
    WT[(size_t)(n0 + ty + r*8) * K + k0 + tx] = f2bf(tile[tx][ty + r*8]);
}

// ---------------- bf16 GEMM: C[M][N] = A[M][K] @ BT[N][K]^T (+epilogue) ----------------
template<bool BIAS, bool RELU, bool RESID, bool OUTBF16>
__global__ __launch_bounds__(256, 2) void gemm_bt(
    const unsigned short* __restrict__ A, const unsigned short* __restrict__ BT,
    const float* __restrict__ bias, const float* __restrict__ resid,
    void* __restrict__ Cp, int M, int N, int K)
{
  constexpr int BM = 128, BN = 128, BK = 64, PK = 72;
  __shared__ __align__(16) unsigned short As[BM*PK];
  __shared__ __align__(16) unsigned short Bs[BN*PK];
  const int tid  = threadIdx.x;
  const int lane = tid & 63;
  const int wave = tid >> 6;
  const int l15 = lane & 15, lh = lane >> 4;
  const size_t bm = (size_t)blockIdx.y * BM, bn = (size_t)blockIdx.x * BN;
  const int wm = (wave >> 1) * 64, wn = (wave & 1) * 64;
  f32x4 acc[4][4] = {};
  bf16x8 ar[4], br[4];
  const int nk = K / BK;

  auto loadG = [&](int kt) {
    #pragma unroll
    for (int q = 0; q < 4; ++q) {
      int c = tid + q*256;
      int row = c >> 3, k0 = (c & 7) * 8;
      ar[q] = *(const bf16x8*)(A  + (bm + row)*(size_t)K + (size_t)kt*BK + k0);
      br[q] = *(const bf16x8*)(BT + (bn + row)*(size_t)K + (size_t)kt*BK + k0);
    }
  };
  loadG(0);
  for (int kt = 0; kt < nk; ++kt) {
    __syncthreads();
    #pragma unroll
    for (int q = 0; q < 4; ++q) {
      int c = tid + q*256;
      int row = c >> 3, k0 = (c & 7) * 8;
      *(bf16x8*)(&As[row*PK + k0]) = ar[q];
      *(bf16x8*)(&Bs[row*PK + k0]) = br[q];
    }
    __syncthreads();
    if (kt + 1 < nk) loadG(kt + 1);
    #pragma unroll
    for (int kk = 0; kk < 2; ++kk) {
      bf16x8 af[4], bfr[4];
      #pragma unroll
      for (int i = 0; i < 4; ++i) {
        af[i]  = *(const bf16x8*)(&As[(wm + i*16 + l15)*PK + kk*32 + lh*8]);
        bfr[i] = *(const bf16x8*)(&Bs[(wn + i*16 + l15)*PK + kk*32 + lh*8]);
      }
      #pragma unroll
      for (int i = 0; i < 4; ++i)
        #pragma unroll
        for (int j = 0; j < 4; ++j)
          acc[i][j] = __builtin_amdgcn_mfma_f32_16x16x32_bf16(af[i], bfr[j], acc[i][j], 0, 0, 0);
    }
  }
  float bv[4];
  if (BIAS) {
    #pragma unroll
    for (int j = 0; j < 4; ++j) bv[j] = bias[bn + wn + j*16 + l15];
  }
  #pragma unroll
  for (int i = 0; i < 4; ++i) {
    #pragma unroll
    for (int r = 0; r < 4; ++r) {
      size_t rrow = bm + wm + i*16 + lh*4 + r;
      #pragma unroll
      for (int j = 0; j < 4; ++j) {
        size_t ccol = bn + wn + j*16 + l15;
        float v = acc[i][j][r];
        if (BIAS)  v += bv[j];
        if (RELU)  v = fmaxf(v, 0.f);
        if (RESID) v += resid[rrow*(size_t)N + ccol];
        if (OUTBF16) ((unsigned short*)Cp)[rrow*(size_t)N + ccol] = f2bf(v);
        else         ((float*)Cp)[rrow*(size_t)N + ccol] = v;
      }
    }
  }
}

// ---------------- fused causal attention, v2 ----------------
// QKV: [4096][6144] bf16 (Q cols 0..2047, K 2048..4095, V 4096..6143)
// head nh, token p -> QKV row b*2048 + nh*128 + (p>>4), col chunk (p&15)*128
// KVBLK=64, QBLK=64 (4 waves x 16 rows). K in LDS row-XOR swizzled;
// V in LDS in MFMA B-fragment order with per-segment XOR swizzle.
__global__ __launch_bounds__(256) void attn_kernel(
    const unsigned short* __restrict__ QKV, unsigned short* __restrict__ O)
{
  constexpr float SCALE = 0.08838834764831845f;  // 1/sqrt(128)
  __shared__ __align__(16) unsigned short Kl[64*128];   // 16 KB, row-XOR
  __shared__ __align__(16) unsigned short Vf[64*128];   // 16 KB, frag-order
  __shared__ __align__(16) unsigned short Pl[4*1024];   // 8 KB, per-wave 16x64 row-XOR
  const int bid = blockIdx.x;
  const int qt = 31 - (bid >> 5);        // heavy q-tiles launch first
  const int nh = bid & 15;
  const int b  = (bid >> 4) & 1;
  const int t = threadIdx.x;
  const int lane = t & 63, wave = t >> 6;
  const int l15 = lane & 15, lh = lane >> 4;
  const int i0 = qt*64 + wave*16;
  const size_t RS = 6144;
  const size_t base = (size_t)b * 2048 * RS;

  // Q fragments for this wave's 16 rows (rows i0..i0+15 all live in one QKV row)
  const unsigned short* qrow = QKV + base + (size_t)(nh*128 + (i0 >> 4)) * RS;
  bf16x8 qf[4];
  #pragma unroll
  for (int c = 0; c < 4; ++c)
    qf[c] = *(const bf16x8*)(qrow + l15*128 + c*32 + lh*8);

  f32x4 of[8] = {};
  float mrun[4], lrun[4];
  #pragma unroll
  for (int r = 0; r < 4; ++r) { mrun[r] = -INFINITY; lrun[r] = 0.f; }

  const int nkt = qt + 1;
  bf16x8 kr[4], vr[4];
  auto loadKV = [&](int kt) {
    #pragma unroll
    for (int q = 0; q < 4; ++q) {
      int c = t + q*256;                       // 0..1023
      int j = c >> 4, dd0 = (c & 15) * 8;
      const size_t grow = base + (size_t)(nh*128 + kt*4 + (j >> 4)) * RS + (j & 15)*128 + dd0;
      kr[q] = *(const bf16x8*)(QKV + grow + 2048);
      vr[q] = *(const bf16x8*)(QKV + grow + 4096);
    }
  };
  loadKV(0);

  for (int kt = 0; kt < nkt; ++kt) {
    __syncthreads();   // previous tile's LDS reads done
    // ---- store K (vector, row-XOR) + V (frag-order scatter) ----
    #pragma unroll
    for (int q = 0; q < 4; ++q) {
      int c = t + q*256;
      int j = c >> 4, dd0 = (c & 15) * 8;
      *(bf16x8*)((char*)Kl + ((j*256 + dd0*2) ^ ((j & 7) << 4))) = kr[q];
      int ks = j >> 5, jq = j & 31;
      int cc = dd0 >> 4;                        // constant over e (dd0&15 in {0,8})
      int wb = ks*8192 + cc*1024 + (((dd0 & 15) + 16*((jq >> 3) & 3)) & ~7)*16 + (jq & 7)*2;
      #pragma unroll
      for (int e = 0; e < 8; ++e)
        *(unsigned short*)((char*)Vf + wb + ((e ^ cc) * 16)) = (unsigned short)vr[q][e];
    }
    __syncthreads();
    if (kt + 1 < nkt) loadKV(kt + 1);           // prefetch in flight during compute

    // ---- QK^T: scores [16 rows][64 cols] per wave ----
    f32x4 sc[4] = {};
    #pragma unroll
    for (int jt = 0; jt < 4; ++jt) {
      int row = jt*16 + l15;
      const char* kb = (const char*)Kl + row*256;
      const int sw = (row & 7) << 4;
      #pragma unroll
      for (int c = 0; c < 4; ++c) {
        bf16x8 kf = *(const bf16x8*)(kb + ((c*64 + lh*16) ^ sw));
        sc[jt] = __builtin_amdgcn_mfma_f32_16x16x32_bf16(qf[c], kf, sc[jt], 0, 0, 0);
      }
    }

    // ---- online softmax (row i = i0+lh*4+r across lanes l15) ----
    float fac[4];
    char* pw = (char*)Pl + wave*2048;
    #pragma unroll
    for (int r = 0; r < 4; ++r) {
      float s0 = sc[0][r]*SCALE, s1 = sc[1][r]*SCALE, s2 = sc[2][r]*SCALE, s3 = sc[3][r]*SCALE;
      if (kt == qt) {            // only the diagonal tile is partially masked
        const int i = i0 + lh*4 + r;
        const int j = kt*64 + l15;
        s0 = (j      > i) ? -INFINITY : s0;
        s1 = (j + 16 > i) ? -INFINITY : s1;
        s2 = (j + 32 > i) ? -INFINITY : s2;
        s3 = (j + 48 > i) ? -INFINITY : s3;
      }
      float mx = fmaxf(fmaxf(s0, s1), fmaxf(s2, s3));
      #pragma unroll
      for (int mk = 1; mk < 16; mk <<= 1) mx = fmaxf(mx, __shfl_xor(mx, mk));
      const float mnew = fmaxf(mrun[r], mx);
      float p0 = __expf(s0 - mnew), p1 = __expf(s1 - mnew);
      float p2 = __expf(s2 - mnew), p3 = __expf(s3 - mnew);
      float psum = (p0 + p1) + (p2 + p3);
      #pragma unroll
      for (int mk = 1; mk < 16; mk <<= 1) psum += __shfl_xor(psum, mk);
      fac[r]  = __expf(mrun[r] - mnew);
      lrun[r] = lrun[r]*fac[r] + psum;
      mrun[r] = mnew;
      const int io = lh*4 + r;
      const int swp = (io & 7) << 4;
      char* pr = pw + io*128;
      *(unsigned short*)(pr + ((     l15*2) ^ swp)) = f2bf(p0);
      *(unsigned short*)(pr + ((32 + l15*2) ^ swp)) = f2bf(p1);
      *(unsigned short*)(pr + ((64 + l15*2) ^ swp)) = f2bf(p2);
      *(unsigned short*)(pr + ((96 + l15*2) ^ swp)) = f2bf(p3);
    }
    #pragma unroll
    for (int c = 0; c < 8; ++c)
      #pragma unroll
      for (int r = 0; r < 4; ++r)
        of[c][r] *= fac[r];

    // ---- P fragments (per-wave LDS transpose, row-XOR) ----
    const char* prd = pw + l15*128;
    const int psw = (l15 & 7) << 4;
    bf16x8 pa0 = *(const bf16x8*)(prd + ((     lh*16) ^ psw));
    bf16x8 pa1 = *(const bf16x8*)(prd + ((64 + lh*16) ^ psw));

    // ---- PV: o[16][128] += P[16][64] @ V[64][128] ----
    #pragma unroll
    for (int c = 0; c < 8; ++c) {
      const char* vb = (const char*)Vf + c*1024 + ((lane ^ c) * 16);
      bf16x8 v0 = *(const bf16x8*)(vb);
      bf16x8 v1 = *(const bf16x8*)(vb + 8192);
      of[c] = __builtin_amdgcn_mfma_f32_16x16x32_bf16(pa0, v0, of[c], 0, 0, 0);
      of[c] = __builtin_amdgcn_mfma_f32_16x16x32_bf16(pa1, v1, of[c], 0, 0, 0);
    }
  }

  // ---- normalize + store ----
  unsigned short* orow = O + ((size_t)(b*2048 + i0))*2048 + nh*128;
  #pragma unroll
  for (int r = 0; r < 4; ++r) {
    const float inv = 1.f / lrun[r];
    #pragma unroll
    for (int c = 0; c < 8; ++c)
      orow[(size_t)(lh*4 + r)*2048 + c*16 + l15] = f2bf(of[c][r]*inv);
  }
}

// ---------------- launcher ----------------
extern "C" void kernel_launch(void* const* d_in, const int* in_sizes, int n_in,
                              void* d_out, int out_size, void* d_ws, size_t ws_size,
                              hipStream_t stream)
{
  const float* x    = (const float*)d_in[0];
  const float* Wq   = (const float*)d_in[2];
  const float* Wk   = (const float*)d_in[3];
  const float* Wv   = (const float*)d_in[4];
  const float* Wo   = (const float*)d_in[5];
  const float* ln1g = (const float*)d_in[6];
  const float* ln1b = (const float*)d_in[7];
  const float* W1   = (const float*)d_in[8];
  const float* b1   = (const float*)d_in[9];
  const float* W2   = (const float*)d_in[10];
  const float* b2   = (const float*)d_in[11];
  const float* ln2g = (const float*)d_in[12];
  const float* ln2b = (const float*)d_in[13];
  float* out = (float*)d_out;

  char* ws = (char*)d_ws;
  unsigned short* WqkvT  = (unsigned short*)(ws);                  // [6144][2048] bf16
  unsigned short* WoT    = (unsigned short*)(ws + 25165824);       // [2048][2048]
  unsigned short* W1T    = (unsigned short*)(ws + 33554432);       // [8192][2048]
  unsigned short* W2T    = (unsigned short*)(ws + 67108864);       // [2048][8192]
  unsigned short* h      = (unsigned short*)(ws + 100663296);      // [4096][2048]
  float*          x2     = (float*)(ws + 117440512);               // [4096][2048] f32
  unsigned short* QKV    = (unsigned short*)(ws + 150994944);      // [4096][6144]
  unsigned short* attn_o = (unsigned short*)(ws + 201326592);      // [4096][2048]
  unsigned short* ff1    = (unsigned short*)(ws + 150994944);      // [4096][8192] aliases QKV+attn_o

  dim3 tb(32, 8);
  transpose_cast<<<dim3(64, 64),  tb, 0, stream>>>(Wq, WqkvT,                2048, 2048);
  transpose_cast<<<dim3(64, 64),  tb, 0, stream>>>(Wk, WqkvT + 2048*2048,    2048, 2048);
  transpose_cast<<<dim3(64, 64),  tb, 0, stream>>>(Wv, WqkvT + 2*2048*2048,  2048, 2048);
  transpose_cast<<<dim3(64, 64),  tb, 0, stream>>>(Wo, WoT,                  2048, 2048);
  transpose_cast<<<dim3(256, 64), tb, 0, stream>>>(W1, W1T,                  2048, 8192);
  transpose_cast<<<dim3(64, 256), tb, 0, stream>>>(W2, W2T,                  8192, 2048);

  ln_kernel<<<4096, 256, 0, stream>>>(x, ln1g, ln1b, h);
  gemm_bt<false,false,false,true><<<dim3(48, 32), 256, 0, stream>>>(
      h, WqkvT, nullptr, nullptr, QKV, 4096, 6144, 2048);
  attn_kernel<<<1024, 256, 0, stream>>>(QKV, attn_o);
  gemm_bt<false,false,true,false><<<dim3(16, 32), 256, 0, stream>>>(
      attn_o, WoT, nullptr, x, x2, 4096, 2048, 2048);
  ln_kernel<<<4096, 256, 0, stream>>>(x2, ln2g, ln2b, h);
  gemm_bt<true,true,false,true><<<dim3(64, 32), 256, 0, stream>>>(
      h, W1T, b1, nullptr, ff1, 4096, 8192, 2048);
  gemm_bt<true,false,true,false><<<dim3(16, 32), 256, 0, stream>>>(
      ff1, W2T, b2, x2, out, 4096, 2048, 8192);
}

// Round 3
// 647.948 us; speedup vs baseline: 1.4807x; 1.0412x over previous
//
#include <hip/hip_runtime.h>
#include <cstdint>

using bf16x8 = __attribute__((ext_vector_type(8))) short;
using f32x4  = __attribute__((ext_vector_type(4))) float;

__device__ __forceinline__ unsigned short f2bf(float f) {
  union { float f; unsigned u; } v; v.f = f;
  unsigned u = v.u;
  u += 0x7fffu + ((u >> 16) & 1u);
  return (unsigned short)(u >> 16);
}

__device__ __forceinline__ void gload_lds16(const unsigned short* g, unsigned short* l) {
  __builtin_amdgcn_global_load_lds(
      (const __attribute__((address_space(1))) unsigned int*)g,
      (__attribute__((address_space(3))) unsigned int*)l, 16, 0, 0);
}

// ---------------- LayerNorm (row of 2048 f32) -> bf16 ----------------
__global__ __launch_bounds__(256) void ln_kernel(
    const float* __restrict__ x, const float* __restrict__ g,
    const float* __restrict__ bb, unsigned short* __restrict__ h)
{
  const int D = 2048;
  const int row = blockIdx.x;
  const float* xr = x + (size_t)row * D;
  const int t = threadIdx.x;
  float4 v0 = ((const float4*)xr)[t];
  float4 v1 = ((const float4*)xr)[t + 256];
  float s  = v0.x+v0.y+v0.z+v0.w + v1.x+v1.y+v1.z+v1.w;
  float ss = v0.x*v0.x+v0.y*v0.y+v0.z*v0.z+v0.w*v0.w
           + v1.x*v1.x+v1.y*v1.y+v1.z*v1.z+v1.w*v1.w;
  #pragma unroll
  for (int off = 1; off < 64; off <<= 1) {
    s  += __shfl_xor(s, off);
    ss += __shfl_xor(ss, off);
  }
  __shared__ float red[8];
  const int wave = t >> 6, lane = t & 63;
  if (lane == 0) { red[wave] = s; red[4+wave] = ss; }
  __syncthreads();
  s  = red[0]+red[1]+red[2]+red[3];
  ss = red[4]+red[5]+red[6]+red[7];
  const float mu   = s * (1.f/2048.f);
  const float var  = ss * (1.f/2048.f) - mu*mu;
  const float rstd = rsqrtf(var + 1e-5f);
  unsigned short* hr = h + (size_t)row * D;
  #pragma unroll
  for (int q = 0; q < 2; ++q) {
    float4 v = q ? v1 : v0;
    int vecidx = t + q*256;
    float4 gg  = ((const float4*)g)[vecidx];
    float4 bv  = ((const float4*)bb)[vecidx];
    ushort4 o;
    o.x = f2bf((v.x-mu)*rstd*gg.x + bv.x);
    o.y = f2bf((v.y-mu)*rstd*gg.y + bv.y);
    o.z = f2bf((v.z-mu)*rstd*gg.z + bv.z);
    o.w = f2bf((v.w-mu)*rstd*gg.w + bv.w);
    *(ushort4*)(hr + vecidx*4) = o;
  }
}

// ---------------- fp32 [K][N] -> bf16 [N][K] transpose+cast ----------------
__global__ __launch_bounds__(256) void transpose_cast(
    const float* __restrict__ W, unsigned short* __restrict__ WT,
    int K, int N)
{
  __shared__ float tile[32][33];
  const int tx = threadIdx.x, ty = threadIdx.y;
  const int n0 = blockIdx.x * 32, k0 = blockIdx.y * 32;
  #pragma unroll
  for (int r = 0; r < 4; ++r)
    tile[ty + r*8][tx] = W[(size_t)(k0 + ty + r*8) * N + n0 + tx];
  __syncthreads();
  #pragma unroll
  for (int r = 0; r < 4; ++r)
    WT[(size_t)(n0 + ty + r*8) * K + k0 + tx] = f2bf(tile[tx][ty + r*8]);
}

// ---------------- 8-phase-style 256-wide bf16 GEMM ----------------
// C[M][N] = A[M][K] @ BT[N][K]^T (+epilogue). BM=256, BK=64, 8 waves (2Mx4N),
// 512 threads. Double-buffered LDS via global_load_lds(16B) with XOR-swizzled
// global source (linear LDS dest) and swizzled ds_read_b128 fragment reads.
// Counted vmcnt at K-tile top; raw s_barrier (no vmcnt(0) drain in main loop).
template<int BN, bool BIAS, bool RELU, bool RESID, bool OUTBF16>
__global__ __launch_bounds__(512, 2) void gemm8(
    const unsigned short* __restrict__ A, const unsigned short* __restrict__ BT,
    const float* __restrict__ bias, const float* __restrict__ resid,
    void* __restrict__ Cp, int M, int N, int K, int nbx)
{
  constexpr int BM = 256, BK = 64;
  constexpr int NREP = BN / 64;       // B fragment repeats per kk (4 or 2)
  constexpr int BLD  = BN / 64;       // B staging instructions per thread
  constexpr int LPK  = 4 + BLD;       // loads per K-tile per thread
  __shared__ __align__(16) unsigned short lds[2][(BM + BN) * BK];

  const int tid  = threadIdx.x;
  const int lane = tid & 63, wave = tid >> 6;
  const int l15 = lane & 15, lh = lane >> 4;
  const int wr = wave >> 2, wc = wave & 3;

  // XCD-aware bijective swizzle (all grids are multiples of 8)
  const int nwg = gridDim.x;
  const int q8  = nwg >> 3;
  const int wg  = blockIdx.x;
  const int swz = (wg & 7) * q8 + (wg >> 3);
  const size_t bm = (size_t)(swz / nbx) * BM;
  const size_t bn = (size_t)(swz % nbx) * BN;

  const int nk = K >> 6;

  auto stage = [&](int buf, int kt) {
    unsigned short* La = &lds[buf][0];
    unsigned short* Lb = &lds[buf][BM * BK];
    #pragma unroll
    for (int qq = 0; qq < 4; ++qq) {
      int idx = qq * 512 + tid;          // 16B chunk id, linear in LDS
      int row = idx >> 3, c = idx & 7;
      int gc = c ^ (row & 7);            // inverse-swizzled source chunk
      gload_lds16(A + (bm + row) * (size_t)K + (size_t)kt * BK + gc * 8,
                  La + idx * 8);
    }
    #pragma unroll
    for (int qq = 0; qq < BLD; ++qq) {
      int idx = qq * 512 + tid;
      int row = idx >> 3, c = idx & 7;
      int gc = c ^ (row & 7);
      gload_lds16(BT + (bn + row) * (size_t)K + (size_t)kt * BK + gc * 8,
                  Lb + idx * 8);
    }
  };

  f32x4 acc[8][NREP] = {};

  stage(0, 0);
  stage(1, 1);

  for (int kt = 0; kt < nk; ++kt) {
    const int buf = kt & 1;
    if (kt < nk - 1) {
      asm volatile("s_waitcnt vmcnt(%0)" :: "i"(LPK) : "memory");
    } else {
      asm volatile("s_waitcnt vmcnt(0)" ::: "memory");
    }
    __builtin_amdgcn_s_barrier();        // all waves' cur-loads landed
    asm volatile("" ::: "memory");

    const unsigned short* La = &lds[buf][0];
    const unsigned short* Lb = &lds[buf][BM * BK];
    bf16x8 bfr[2][NREP];
    #pragma unroll
    for (int p = 0; p < 4; ++p) {
      if (p == 0) {
        #pragma unroll
        for (int kk = 0; kk < 2; ++kk)
          #pragma unroll
          for (int n = 0; n < NREP; ++n) {
            int brow = wc * (BN / 4) + n * 16 + l15;
            bfr[kk][n] = *(const bf16x8*)(Lb + brow * 64 +
                           ((kk * 32 + lh * 8) ^ ((brow & 7) << 3)));
          }
      }
      bf16x8 af[2][2];
      #pragma unroll
      for (int mi = 0; mi < 2; ++mi) {
        int arow = wr * 128 + (p * 2 + mi) * 16 + l15;
        #pragma unroll
        for (int kk = 0; kk < 2; ++kk)
          af[mi][kk] = *(const bf16x8*)(La + arow * 64 +
                         ((kk * 32 + lh * 8) ^ ((arow & 7) << 3)));
      }
      asm volatile("" ::: "memory");
      __builtin_amdgcn_s_barrier();
      __builtin_amdgcn_s_setprio(1);
      #pragma unroll
      for (int mi = 0; mi < 2; ++mi)
        #pragma unroll
        for (int n = 0; n < NREP; ++n)
          #pragma unroll
          for (int kk = 0; kk < 2; ++kk)
            acc[p*2+mi][n] = __builtin_amdgcn_mfma_f32_16x16x32_bf16(
                af[mi][kk], bfr[kk][n], acc[p*2+mi][n], 0, 0, 0);
      __builtin_amdgcn_s_setprio(0);
      asm volatile("" ::: "memory");
      __builtin_amdgcn_s_barrier();      // after p==3: all reads of buf done
    }
    if (kt + 2 < nk) stage(buf, kt + 2); // refill just-consumed buffer
  }

  // ---- epilogue ----
  float bv[NREP];
  if (BIAS) {
    #pragma unroll
    for (int n = 0; n < NREP; ++n) bv[n] = bias[bn + wc*(BN/4) + n*16 + l15];
  }
  #pragma unroll
  for (int m = 0; m < 8; ++m) {
    #pragma unroll
    for (int r = 0; r < 4; ++r) {
      size_t rrow = bm + wr*128 + m*16 + lh*4 + r;
      #pragma unroll
      for (int n = 0; n < NREP; ++n) {
        size_t ccol = bn + wc*(BN/4) + n*16 + l15;
        float v = acc[m][n][r];
        if (BIAS)  v += bv[n];
        if (RELU)  v = fmaxf(v, 0.f);
        if (RESID) v += resid[rrow*(size_t)N + ccol];
        if (OUTBF16) ((unsigned short*)Cp)[rrow*(size_t)N + ccol] = f2bf(v);
        else         ((float*)Cp)[rrow*(size_t)N + ccol] = v;
      }
    }
  }
}

// ---------------- fused causal attention (unchanged from r1) ----------------
__global__ __launch_bounds__(256) void attn_kernel(
    const unsigned short* __restrict__ QKV, unsigned short* __restrict__ O)
{
  constexpr float SCALE = 0.08838834764831845f;  // 1/sqrt(128)
  __shared__ __align__(16) unsigned short Kl[64*128];
  __shared__ __align__(16) unsigned short Vf[64*128];
  __shared__ __align__(16) unsigned short Pl[4*1024];
  const int bid = blockIdx.x;
  const int qt = 31 - (bid >> 5);
  const int nh = bid & 15;
  const int b  = (bid >> 4) & 1;
  const int t = threadIdx.x;
  const int lane = t & 63, wave = t >> 6;
  const int l15 = lane & 15, lh = lane >> 4;
  const int i0 = qt*64 + wave*16;
  const size_t RS = 6144;
  const size_t base = (size_t)b * 2048 * RS;

  const unsigned short* qrow = QKV + base + (size_t)(nh*128 + (i0 >> 4)) * RS;
  bf16x8 qf[4];
  #pragma unroll
  for (int c = 0; c < 4; ++c)
    qf[c] = *(const bf16x8*)(qrow + l15*128 + c*32 + lh*8);

  f32x4 of[8] = {};
  float mrun[4], lrun[4];
  #pragma unroll
  for (int r = 0; r < 4; ++r) { mrun[r] = -INFINITY; lrun[r] = 0.f; }

  const int nkt = qt + 1;
  bf16x8 kr[4], vr[4];
  auto loadKV = [&](int kt) {
    #pragma unroll
    for (int q = 0; q < 4; ++q) {
      int c = t + q*256;
      int j = c >> 4, dd0 = (c & 15) * 8;
      const size_t grow = base + (size_t)(nh*128 + kt*4 + (j >> 4)) * RS + (j & 15)*128 + dd0;
      kr[q] = *(const bf16x8*)(QKV + grow + 2048);
      vr[q] = *(const bf16x8*)(QKV + grow + 4096);
    }
  };
  loadKV(0);

  for (int kt = 0; kt < nkt; ++kt) {
    __syncthreads();
    #pragma unroll
    for (int q = 0; q < 4; ++q) {
      int c = t + q*256;
      int j = c >> 4, dd0 = (c & 15) * 8;
      *(bf16x8*)((char*)Kl + ((j*256 + dd0*2) ^ ((j & 7) << 4))) = kr[q];
      int ks = j >> 5, jq = j & 31;
      int cc = dd0 >> 4;
      int wb = ks*8192 + cc*1024 + (((dd0 & 15) + 16*((jq >> 3) & 3)) & ~7)*16 + (jq & 7)*2;
      #pragma unroll
      for (int e = 0; e < 8; ++e)
        *(unsigned short*)((char*)Vf + wb + ((e ^ cc) * 16)) = (unsigned short)vr[q][e];
    }
    __syncthreads();
    if (kt + 1 < nkt) loadKV(kt + 1);

    f32x4 sc[4] = {};
    #pragma unroll
    for (int jt = 0; jt < 4; ++jt) {
      int row = jt*16 + l15;
      const char* kb = (const char*)Kl + row*256;
      const int sw = (row & 7) << 4;
      #pragma unroll
      for (int c = 0; c < 4; ++c) {
        bf16x8 kf = *(const bf16x8*)(kb + ((c*64 + lh*16) ^ sw));
        sc[jt] = __builtin_amdgcn_mfma_f32_16x16x32_bf16(qf[c], kf, sc[jt], 0, 0, 0);
      }
    }

    float fac[4];
    char* pw = (char*)Pl + wave*2048;
    #pragma unroll
    for (int r = 0; r < 4; ++r) {
      float s0 = sc[0][r]*SCALE, s1 = sc[1][r]*SCALE, s2 = sc[2][r]*SCALE, s3 = sc[3][r]*SCALE;
      if (kt == qt) {
        const int i = i0 + lh*4 + r;
        const int j = kt*64 + l15;
        s0 = (j      > i) ? -INFINITY : s0;
        s1 = (j + 16 > i) ? -INFINITY : s1;
        s2 = (j + 32 > i) ? -INFINITY : s2;
        s3 = (j + 48 > i) ? -INFINITY : s3;
      }
      float mx = fmaxf(fmaxf(s0, s1), fmaxf(s2, s3));
      #pragma unroll
      for (int mk = 1; mk < 16; mk <<= 1) mx = fmaxf(mx, __shfl_xor(mx, mk));
      const float mnew = fmaxf(mrun[r], mx);
      float p0 = __expf(s0 - mnew), p1 = __expf(s1 - mnew);
      float p2 = __expf(s2 - mnew), p3 = __expf(s3 - mnew);
      float psum = (p0 + p1) + (p2 + p3);
      #pragma unroll
      for (int mk = 1; mk < 16; mk <<= 1) psum += __shfl_xor(psum, mk);
      fac[r]  = __expf(mrun[r] - mnew);
      lrun[r] = lrun[r]*fac[r] + psum;
      mrun[r] = mnew;
      const int io = lh*4 + r;
      const int swp = (io & 7) << 4;
      char* pr = pw + io*128;
      *(unsigned short*)(pr + ((     l15*2) ^ swp)) = f2bf(p0);
      *(unsigned short*)(pr + ((32 + l15*2) ^ swp)) = f2bf(p1);
      *(unsigned short*)(pr + ((64 + l15*2) ^ swp)) = f2bf(p2);
      *(unsigned short*)(pr + ((96 + l15*2) ^ swp)) = f2bf(p3);
    }
    #pragma unroll
    for (int c = 0; c < 8; ++c)
      #pragma unroll
      for (int r = 0; r < 4; ++r)
        of[c][r] *= fac[r];

    const char* prd = pw + l15*128;
    const int psw = (l15 & 7) << 4;
    bf16x8 pa0 = *(const bf16x8*)(prd + ((     lh*16) ^ psw));
    bf16x8 pa1 = *(const bf16x8*)(prd + ((64 + lh*16) ^ psw));

    #pragma unroll
    for (int c = 0; c < 8; ++c) {
      const char* vb = (const char*)Vf + c*1024 + ((lane ^ c) * 16);
      bf16x8 v0 = *(const bf16x8*)(vb);
      bf16x8 v1 = *(const bf16x8*)(vb + 8192);
      of[c] = __builtin_amdgcn_mfma_f32_16x16x32_bf16(pa0, v0, of[c], 0, 0, 0);
      of[c] = __builtin_amdgcn_mfma_f32_16x16x32_bf16(pa1, v1, of[c], 0, 0, 0);
    }
  }

  unsigned short* orow = O + ((size_t)(b*2048 + i0))*2048 + nh*128;
  #pragma unroll
  for (int r = 0; r < 4; ++r) {
    const float inv = 1.f / lrun[r];
    #pragma unroll
    for (int c = 0; c < 8; ++c)
      orow[(size_t)(lh*4 + r)*2048 + c*16 + l15] = f2bf(of[c][r]*inv);
  }
}

// ---------------- launcher ----------------
extern "C" void kernel_launch(void* const* d_in, const int* in_sizes, int n_in,
                              void* d_out, int out_size, void* d_ws, size_t ws_size,
                              hipStream_t stream)
{
  const float* x    = (const float*)d_in[0];
  const float* Wq   = (const float*)d_in[2];
  const float* Wk   = (const float*)d_in[3];
  const float* Wv   = (const float*)d_in[4];
  const float* Wo   = (const float*)d_in[5];
  const float* ln1g = (const float*)d_in[6];
  const float* ln1b = (const float*)d_in[7];
  const float* W1   = (const float*)d_in[8];
  const float* b1   = (const float*)d_in[9];
  const float* W2   = (const float*)d_in[10];
  const float* b2   = (const float*)d_in[11];
  const float* ln2g = (const float*)d_in[12];
  const float* ln2b = (const float*)d_in[13];
  float* out = (float*)d_out;

  char* ws = (char*)d_ws;
  unsigned short* WqkvT  = (unsigned short*)(ws);                  // [6144][2048] bf16
  unsigned short* WoT    = (unsigned short*)(ws + 25165824);       // [2048][2048]
  unsigned short* W1T    = (unsigned short*)(ws + 33554432);       // [8192][2048]
  unsigned short* W2T    = (unsigned short*)(ws + 67108864);       // [2048][8192]
  unsigned short* h      = (unsigned short*)(ws + 100663296);      // [4096][2048]
  float*          x2     = (float*)(ws + 117440512);               // [4096][2048] f32
  unsigned short* QKV    = (unsigned short*)(ws + 150994944);      // [4096][6144]
  unsigned short* attn_o = (unsigned short*)(ws + 201326592);      // [4096][2048]
  unsigned short* ff1    = (unsigned short*)(ws + 150994944);      // [4096][8192] aliases QKV+attn_o

  dim3 tb(32, 8);
  transpose_cast<<<dim3(64, 64),  tb, 0, stream>>>(Wq, WqkvT,                2048, 2048);
  transpose_cast<<<dim3(64, 64),  tb, 0, stream>>>(Wk, WqkvT + 2048*2048,    2048, 2048);
  transpose_cast<<<dim3(64, 64),  tb, 0, stream>>>(Wv, WqkvT + 2*2048*2048,  2048, 2048);
  transpose_cast<<<dim3(64, 64),  tb, 0, stream>>>(Wo, WoT,                  2048, 2048);
  transpose_cast<<<dim3(256, 64), tb, 0, stream>>>(W1, W1T,                  2048, 8192);
  transpose_cast<<<dim3(64, 256), tb, 0, stream>>>(W2, W2T,                  8192, 2048);

  ln_kernel<<<4096, 256, 0, stream>>>(x, ln1g, ln1b, h);
  // QKV = h @ [Wq|Wk|Wv]   (M=4096, N=6144, K=2048) -> 16x24 = 384 blocks
  gemm8<256,false,false,false,true><<<384, 512, 0, stream>>>(
      h, WqkvT, nullptr, nullptr, QKV, 4096, 6144, 2048, 24);
  attn_kernel<<<1024, 256, 0, stream>>>(QKV, attn_o);
  // x2 = x + attn_o @ Wo   (N=2048) -> BN=128, 16x16 = 256 blocks
  gemm8<128,false,false,true,false><<<256, 512, 0, stream>>>(
      attn_o, WoT, nullptr, x, x2, 4096, 2048, 2048, 16);
  ln_kernel<<<4096, 256, 0, stream>>>(x2, ln2g, ln2b, h);
  // ff1 = relu(h2 @ W1 + b1)  (N=8192) -> 16x32 = 512 blocks
  gemm8<256,true,true,false,true><<<512, 512, 0, stream>>>(
      h, W1T, b1, nullptr, ff1, 4096, 8192, 2048, 32);
  // out = x2 + ff1 @ W2 + b2  (N=2048, K=8192) -> BN=128, 256 blocks
  gemm8<128,true,false,true,false><<<256, 512, 0, stream>>>(
      ff1, W2T, b2, x2, out, 4096, 2048, 8192, 16);
}

// Round 4
// 626.498 us; speedup vs baseline: 1.5314x; 1.0342x over previous
//
#include <hip/hip_runtime.h>
#include <cstdint>

using bf16x8 = __attribute__((ext_vector_type(8))) short;
using f32x4  = __attribute__((ext_vector_type(4))) float;

__device__ __forceinline__ unsigned short f2bf(float f) {
  union { float f; unsigned u; } v; v.f = f;
  unsigned u = v.u;
  u += 0x7fffu + ((u >> 16) & 1u);
  return (unsigned short)(u >> 16);
}

__device__ __forceinline__ void gload_lds16(const unsigned short* g, unsigned short* l) {
  __builtin_amdgcn_global_load_lds(
      (const __attribute__((address_space(1))) unsigned int*)g,
      (__attribute__((address_space(3))) unsigned int*)l, 16, 0, 0);
}

// ---------------- LayerNorm (row of 2048 f32) -> bf16 ----------------
__global__ __launch_bounds__(256) void ln_kernel(
    const float* __restrict__ x, const float* __restrict__ g,
    const float* __restrict__ bb, unsigned short* __restrict__ h)
{
  const int D = 2048;
  const int row = blockIdx.x;
  const float* xr = x + (size_t)row * D;
  const int t = threadIdx.x;
  float4 v0 = ((const float4*)xr)[t];
  float4 v1 = ((const float4*)xr)[t + 256];
  float s  = v0.x+v0.y+v0.z+v0.w + v1.x+v1.y+v1.z+v1.w;
  float ss = v0.x*v0.x+v0.y*v0.y+v0.z*v0.z+v0.w*v0.w
           + v1.x*v1.x+v1.y*v1.y+v1.z*v1.z+v1.w*v1.w;
  #pragma unroll
  for (int off = 1; off < 64; off <<= 1) {
    s  += __shfl_xor(s, off);
    ss += __shfl_xor(ss, off);
  }
  __shared__ float red[8];
  const int wave = t >> 6, lane = t & 63;
  if (lane == 0) { red[wave] = s; red[4+wave] = ss; }
  __syncthreads();
  s  = red[0]+red[1]+red[2]+red[3];
  ss = red[4]+red[5]+red[6]+red[7];
  const float mu   = s * (1.f/2048.f);
  const float var  = ss * (1.f/2048.f) - mu*mu;
  const float rstd = rsqrtf(var + 1e-5f);
  unsigned short* hr = h + (size_t)row * D;
  #pragma unroll
  for (int q = 0; q < 2; ++q) {
    float4 v = q ? v1 : v0;
    int vecidx = t + q*256;
    float4 gg  = ((const float4*)g)[vecidx];
    float4 bv  = ((const float4*)bb)[vecidx];
    ushort4 o;
    o.x = f2bf((v.x-mu)*rstd*gg.x + bv.x);
    o.y = f2bf((v.y-mu)*rstd*gg.y + bv.y);
    o.z = f2bf((v.z-mu)*rstd*gg.z + bv.z);
    o.w = f2bf((v.w-mu)*rstd*gg.w + bv.w);
    *(ushort4*)(hr + vecidx*4) = o;
  }
}

// ---------------- fp32 [K][N] -> bf16 [N][K] transpose+cast ----------------
__global__ __launch_bounds__(256) void transpose_cast(
    const float* __restrict__ W, unsigned short* __restrict__ WT,
    int K, int N)
{
  __shared__ float tile[32][33];
  const int tx = threadIdx.x, ty = threadIdx.y;
  const int n0 = blockIdx.x * 32, k0 = blockIdx.y * 32;
  #pragma unroll
  for (int r = 0; r < 4; ++r)
    tile[ty + r*8][tx] = W[(size_t)(k0 + ty + r*8) * N + n0 + tx];
  __syncthreads();
  #pragma unroll
  for (int r = 0; r < 4; ++r)
    WT[(size_t)(n0 + ty + r*8) * K + k0 + tx] = f2bf(tile[tx][ty + r*8]);
}

// ---------------- 8-phase bf16 GEMM, distributed staging ----------------
// C[M][N] = A[M][K] @ BT[N][K]^T (+epilogue). BN=256, BK=64, 8 waves (2Mx4N),
// 512 threads. Phase p consumes A rows [64p,64p+64) (all waves) and all B in
// phase 0, so tile kt+2's global_load_lds can be issued 2-per-phase into the
// just-freed regions of the buffer currently being read. Counted vmcnt at tile
// top (never 0 in steady state); raw s_barrier; setprio around 16-MFMA clusters.
template<int BM, bool BIAS, bool RELU, bool RESID, bool OUTBF16>
__global__ __launch_bounds__(512, 2) void gemm8(
    const unsigned short* __restrict__ A, const unsigned short* __restrict__ BT,
    const float* __restrict__ bias, const float* __restrict__ resid,
    void* __restrict__ Cp, int M, int N, int K, int nbx)
{
  constexpr int BN = 256, BK = 64;
  constexpr int MPH = BM / 64;           // phases per K-tile (4 or 2)
  constexpr int AQ  = BM / 64;           // A stage-quarters (64 rows each)
  constexpr int LPK = AQ + 4;            // loads per K-tile per thread
  __shared__ __align__(16) unsigned short lds[2][(BM + BN) * BK];

  const int tid  = threadIdx.x;
  const int lane = tid & 63, wave = tid >> 6;
  const int l15 = lane & 15, lh = lane >> 4;
  const int wr = wave >> 2, wc = wave & 3;

  // XCD-aware bijective swizzle (all grids are multiples of 8)
  const int nwg = gridDim.x;
  const int q8  = nwg >> 3;
  const int wg  = blockIdx.x;
  const int swz = (wg & 7) * q8 + (wg >> 3);
  const size_t bm = (size_t)(swz / nbx) * BM;
  const size_t bn = (size_t)(swz % nbx) * BN;
  const int nk = K >> 6;

  auto stageA = [&](int buf, int kt, int qq) {
    int idx = qq * 512 + tid;            // rows [64*qq, 64*qq+64)
    int row = idx >> 3, c = idx & 7, gc = c ^ (row & 7);
    gload_lds16(A + (bm + row) * (size_t)K + (size_t)kt * BK + gc * 8,
                &lds[buf][0] + idx * 8);
  };
  auto stageB = [&](int buf, int kt, int qq) {
    int idx = qq * 512 + tid;
    int row = idx >> 3, c = idx & 7, gc = c ^ (row & 7);
    gload_lds16(BT + (bn + row) * (size_t)K + (size_t)kt * BK + gc * 8,
                &lds[buf][BM * BK] + idx * 8);
  };

  f32x4 acc[MPH * 2][4] = {};

  #pragma unroll
  for (int qq = 0; qq < AQ; ++qq) stageA(0, 0, qq);
  #pragma unroll
  for (int qq = 0; qq < 4; ++qq)  stageB(0, 0, qq);
  #pragma unroll
  for (int qq = 0; qq < AQ; ++qq) stageA(1, 1, qq);
  #pragma unroll
  for (int qq = 0; qq < 4; ++qq)  stageB(1, 1, qq);

  for (int kt = 0; kt < nk; ++kt) {
    const int buf = kt & 1;
    if (kt < nk - 1) asm volatile("s_waitcnt vmcnt(%0)" :: "i"(LPK) : "memory");
    else             asm volatile("s_waitcnt vmcnt(0)" ::: "memory");
    __builtin_amdgcn_s_barrier();        // all waves' tile-kt loads landed
    asm volatile("" ::: "memory");

    const unsigned short* La = &lds[buf][0];
    const unsigned short* Lb = &lds[buf][BM * BK];
    bf16x8 bfr[2][4];
    const bool pf = (kt + 2 < nk);

    #pragma unroll
    for (int p = 0; p < MPH; ++p) {
      // stage tile kt+2 into regions freed by phase p-1 (same buffer!)
      if (p > 0 && pf) {
        if (MPH == 4) { stageA(buf, kt + 2, p - 1); stageB(buf, kt + 2, p - 1); }
        else          { stageA(buf, kt + 2, 0);
                        stageB(buf, kt + 2, 0); stageB(buf, kt + 2, 1); }
      }
      if (p == 0) {
        #pragma unroll
        for (int kk = 0; kk < 2; ++kk)
          #pragma unroll
          for (int n = 0; n < 4; ++n) {
            int brow = wc * 64 + n * 16 + l15;
            bfr[kk][n] = *(const bf16x8*)(Lb + brow * 64 +
                           ((kk * 32 + lh * 8) ^ ((brow & 7) << 3)));
          }
      }
      bf16x8 af[2][2];
      #pragma unroll
      for (int mi = 0; mi < 2; ++mi) {
        int arow = (p * 4 + wr * 2 + mi) * 16 + l15;   // phase p: rows [64p,64p+64)
        #pragma unroll
        for (int kk = 0; kk < 2; ++kk)
          af[mi][kk] = *(const bf16x8*)(La + arow * 64 +
                         ((kk * 32 + lh * 8) ^ ((arow & 7) << 3)));
      }
      asm volatile("" ::: "memory");
      __builtin_amdgcn_s_barrier();
      __builtin_amdgcn_s_setprio(1);
      #pragma unroll
      for (int mi = 0; mi < 2; ++mi)
        #pragma unroll
        for (int n = 0; n < 4; ++n)
          #pragma unroll
          for (int kk = 0; kk < 2; ++kk)
            acc[p*2+mi][n] = __builtin_amdgcn_mfma_f32_16x16x32_bf16(
                af[mi][kk], bfr[kk][n], acc[p*2+mi][n], 0, 0, 0);
      __builtin_amdgcn_s_setprio(0);
      asm volatile("" ::: "memory");
      __builtin_amdgcn_s_barrier();      // phase p regions now dead
    }
    if (pf) {                            // last freed quarter(s)
      if (MPH == 4) { stageA(buf, kt + 2, 3); stageB(buf, kt + 2, 3); }
      else          { stageA(buf, kt + 2, 1);
                      stageB(buf, kt + 2, 2); stageB(buf, kt + 2, 3); }
    }
  }

  // ---- epilogue ----
  float bv[4];
  if (BIAS) {
    #pragma unroll
    for (int n = 0; n < 4; ++n) bv[n] = bias[bn + wc*64 + n*16 + l15];
  }
  #pragma unroll
  for (int p = 0; p < MPH; ++p) {
    #pragma unroll
    for (int mi = 0; mi < 2; ++mi) {
      #pragma unroll
      for (int r = 0; r < 4; ++r) {
        size_t rrow = bm + (size_t)(p*4 + wr*2 + mi)*16 + lh*4 + r;
        #pragma unroll
        for (int n = 0; n < 4; ++n) {
          size_t ccol = bn + wc*64 + n*16 + l15;
          float v = acc[p*2+mi][n][r];
          if (BIAS)  v += bv[n];
          if (RELU)  v = fmaxf(v, 0.f);
          if (RESID) v += resid[rrow*(size_t)N + ccol];
          if (OUTBF16) ((unsigned short*)Cp)[rrow*(size_t)N + ccol] = f2bf(v);
          else         ((float*)Cp)[rrow*(size_t)N + ccol] = v;
        }
      }
    }
  }
}

// ---------------- fused causal attention (unchanged) ----------------
__global__ __launch_bounds__(256) void attn_kernel(
    const unsigned short* __restrict__ QKV, unsigned short* __restrict__ O)
{
  constexpr float SCALE = 0.08838834764831845f;  // 1/sqrt(128)
  __shared__ __align__(16) unsigned short Kl[64*128];
  __shared__ __align__(16) unsigned short Vf[64*128];
  __shared__ __align__(16) unsigned short Pl[4*1024];
  const int bid = blockIdx.x;
  const int qt = 31 - (bid >> 5);
  const int nh = bid & 15;
  const int b  = (bid >> 4) & 1;
  const int t = threadIdx.x;
  const int lane = t & 63, wave = t >> 6;
  const int l15 = lane & 15, lh = lane >> 4;
  const int i0 = qt*64 + wave*16;
  const size_t RS = 6144;
  const size_t base = (size_t)b * 2048 * RS;

  const unsigned short* qrow = QKV + base + (size_t)(nh*128 + (i0 >> 4)) * RS;
  bf16x8 qf[4];
  #pragma unroll
  for (int c = 0; c < 4; ++c)
    qf[c] = *(const bf16x8*)(qrow + l15*128 + c*32 + lh*8);

  f32x4 of[8] = {};
  float mrun[4], lrun[4];
  #pragma unroll
  for (int r = 0; r < 4; ++r) { mrun[r] = -INFINITY; lrun[r] = 0.f; }

  const int nkt = qt + 1;
  bf16x8 kr[4], vr[4];
  auto loadKV = [&](int kt) {
    #pragma unroll
    for (int q = 0; q < 4; ++q) {
      int c = t + q*256;
      int j = c >> 4, dd0 = (c & 15) * 8;
      const size_t grow = base + (size_t)(nh*128 + kt*4 + (j >> 4)) * RS + (j & 15)*128 + dd0;
      kr[q] = *(const bf16x8*)(QKV + grow + 2048);
      vr[q] = *(const bf16x8*)(QKV + grow + 4096);
    }
  };
  loadKV(0);

  for (int kt = 0; kt < nkt; ++kt) {
    __syncthreads();
    #pragma unroll
    for (int q = 0; q < 4; ++q) {
      int c = t + q*256;
      int j = c >> 4, dd0 = (c & 15) * 8;
      *(bf16x8*)((char*)Kl + ((j*256 + dd0*2) ^ ((j & 7) << 4))) = kr[q];
      int ks = j >> 5, jq = j & 31;
      int cc = dd0 >> 4;
      int wb = ks*8192 + cc*1024 + (((dd0 & 15) + 16*((jq >> 3) & 3)) & ~7)*16 + (jq & 7)*2;
      #pragma unroll
      for (int e = 0; e < 8; ++e)
        *(unsigned short*)((char*)Vf + wb + ((e ^ cc) * 16)) = (unsigned short)vr[q][e];
    }
    __syncthreads();
    if (kt + 1 < nkt) loadKV(kt + 1);

    f32x4 sc[4] = {};
    #pragma unroll
    for (int jt = 0; jt < 4; ++jt) {
      int row = jt*16 + l15;
      const char* kb = (const char*)Kl + row*256;
      const int sw = (row & 7) << 4;
      #pragma unroll
      for (int c = 0; c < 4; ++c) {
        bf16x8 kf = *(const bf16x8*)(kb + ((c*64 + lh*16) ^ sw));
        sc[jt] = __builtin_amdgcn_mfma_f32_16x16x32_bf16(qf[c], kf, sc[jt], 0, 0, 0);
      }
    }

    float fac[4];
    char* pw = (char*)Pl + wave*2048;
    #pragma unroll
    for (int r = 0; r < 4; ++r) {
      float s0 = sc[0][r]*SCALE, s1 = sc[1][r]*SCALE, s2 = sc[2][r]*SCALE, s3 = sc[3][r]*SCALE;
      if (kt == qt) {
        const int i = i0 + lh*4 + r;
        const int j = kt*64 + l15;
        s0 = (j      > i) ? -INFINITY : s0;
        s1 = (j + 16 > i) ? -INFINITY : s1;
        s2 = (j + 32 > i) ? -INFINITY : s2;
        s3 = (j + 48 > i) ? -INFINITY : s3;
      }
      float mx = fmaxf(fmaxf(s0, s1), fmaxf(s2, s3));
      #pragma unroll
      for (int mk = 1; mk < 16; mk <<= 1) mx = fmaxf(mx, __shfl_xor(mx, mk));
      const float mnew = fmaxf(mrun[r], mx);
      float p0 = __expf(s0 - mnew), p1 = __expf(s1 - mnew);
      float p2 = __expf(s2 - mnew), p3 = __expf(s3 - mnew);
      float psum = (p0 + p1) + (p2 + p3);
      #pragma unroll
      for (int mk = 1; mk < 16; mk <<= 1) psum += __shfl_xor(psum, mk);
      fac[r]  = __expf(mrun[r] - mnew);
      lrun[r] = lrun[r]*fac[r] + psum;
      mrun[r] = mnew;
      const int io = lh*4 + r;
      const int swp = (io & 7) << 4;
      char* pr = pw + io*128;
      *(unsigned short*)(pr + ((     l15*2) ^ swp)) = f2bf(p0);
      *(unsigned short*)(pr + ((32 + l15*2) ^ swp)) = f2bf(p1);
      *(unsigned short*)(pr + ((64 + l15*2) ^ swp)) = f2bf(p2);
      *(unsigned short*)(pr + ((96 + l15*2) ^ swp)) = f2bf(p3);
    }
    #pragma unroll
    for (int c = 0; c < 8; ++c)
      #pragma unroll
      for (int r = 0; r < 4; ++r)
        of[c][r] *= fac[r];

    const char* prd = pw + l15*128;
    const int psw = (l15 & 7) << 4;
    bf16x8 pa0 = *(const bf16x8*)(prd + ((     lh*16) ^ psw));
    bf16x8 pa1 = *(const bf16x8*)(prd + ((64 + lh*16) ^ psw));

    #pragma unroll
    for (int c = 0; c < 8; ++c) {
      const char* vb = (const char*)Vf + c*1024 + ((lane ^ c) * 16);
      bf16x8 v0 = *(const bf16x8*)(vb);
      bf16x8 v1 = *(const bf16x8*)(vb + 8192);
      of[c] = __builtin_amdgcn_mfma_f32_16x16x32_bf16(pa0, v0, of[c], 0, 0, 0);
      of[c] = __builtin_amdgcn_mfma_f32_16x16x32_bf16(pa1, v1, of[c], 0, 0, 0);
    }
  }

  unsigned short* orow = O + ((size_t)(b*2048 + i0))*2048 + nh*128;
  #pragma unroll
  for (int r = 0; r < 4; ++r) {
    const float inv = 1.f / lrun[r];
    #pragma unroll
    for (int c = 0; c < 8; ++c)
      orow[(size_t)(lh*4 + r)*2048 + c*16 + l15] = f2bf(of[c][r]*inv);
  }
}

// ---------------- launcher ----------------
extern "C" void kernel_launch(void* const* d_in, const int* in_sizes, int n_in,
                              void* d_out, int out_size, void* d_ws, size_t ws_size,
                              hipStream_t stream)
{
  const float* x    = (const float*)d_in[0];
  const float* Wq   = (const float*)d_in[2];
  const float* Wk   = (const float*)d_in[3];
  const float* Wv   = (const float*)d_in[4];
  const float* Wo   = (const float*)d_in[5];
  const float* ln1g = (const float*)d_in[6];
  const float* ln1b = (const float*)d_in[7];
  const float* W1   = (const float*)d_in[8];
  const float* b1   = (const float*)d_in[9];
  const float* W2   = (const float*)d_in[10];
  const float* b2   = (const float*)d_in[11];
  const float* ln2g = (const float*)d_in[12];
  const float* ln2b = (const float*)d_in[13];
  float* out = (float*)d_out;

  char* ws = (char*)d_ws;
  unsigned short* WqkvT  = (unsigned short*)(ws);                  // [6144][2048] bf16
  unsigned short* WoT    = (unsigned short*)(ws + 25165824);       // [2048][2048]
  unsigned short* W1T    = (unsigned short*)(ws + 33554432);       // [8192][2048]
  unsigned short* W2T    = (unsigned short*)(ws + 67108864);       // [2048][8192]
  unsigned short* h      = (unsigned short*)(ws + 100663296);      // [4096][2048]
  float*          x2     = (float*)(ws + 117440512);               // [4096][2048] f32
  unsigned short* QKV    = (unsigned short*)(ws + 150994944);      // [4096][6144]
  unsigned short* attn_o = (unsigned short*)(ws + 201326592);      // [4096][2048]
  unsigned short* ff1    = (unsigned short*)(ws + 150994944);      // [4096][8192] aliases QKV+attn_o

  dim3 tb(32, 8);
  transpose_cast<<<dim3(64, 64),  tb, 0, stream>>>(Wq, WqkvT,                2048, 2048);
  transpose_cast<<<dim3(64, 64),  tb, 0, stream>>>(Wk, WqkvT + 2048*2048,    2048, 2048);
  transpose_cast<<<dim3(64, 64),  tb, 0, stream>>>(Wv, WqkvT + 2*2048*2048,  2048, 2048);
  transpose_cast<<<dim3(64, 64),  tb, 0, stream>>>(Wo, WoT,                  2048, 2048);
  transpose_cast<<<dim3(256, 64), tb, 0, stream>>>(W1, W1T,                  2048, 8192);
  transpose_cast<<<dim3(64, 256), tb, 0, stream>>>(W2, W2T,                  8192, 2048);

  ln_kernel<<<4096, 256, 0, stream>>>(x, ln1g, ln1b, h);
  // QKV = h @ [Wq|Wk|Wv]   (M=4096, N=6144, K=2048): 16x24 = 384 blocks
  gemm8<256,false,false,false,true><<<384, 512, 0, stream>>>(
      h, WqkvT, nullptr, nullptr, QKV, 4096, 6144, 2048, 24);
  attn_kernel<<<1024, 256, 0, stream>>>(QKV, attn_o);
  // x2 = x + attn_o @ Wo   (N=2048): BM=128 -> 32x8 = 256 blocks
  gemm8<128,false,false,true,false><<<256, 512, 0, stream>>>(
      attn_o, WoT, nullptr, x, x2, 4096, 2048, 2048, 8);
  ln_kernel<<<4096, 256, 0, stream>>>(x2, ln2g, ln2b, h);
  // ff1 = relu(h2 @ W1 + b1)  (N=8192): 16x32 = 512 blocks
  gemm8<256,true,true,false,true><<<512, 512, 0, stream>>>(
      h, W1T, b1, nullptr, ff1, 4096, 8192, 2048, 32);
  // out = x2 + ff1 @ W2 + b2  (N=2048, K=8192): BM=128 -> 256 blocks
  gemm8<128,true,false,true,false><<<256, 512, 0, stream>>>(
      ff1, W2T, b2, x2, out, 4096, 2048, 8192, 8);
}